// Round 18
// baseline (6390.539 us; speedup 1.0000x reference)
//
#include <hip/hip_runtime.h>
#include <hip/hip_bf16.h>

// L=512, B=64, D=H=512, 3H=1536.
//  pq_k : Ep = exp(2·v@Wp^T), Eq = exp(2·v@Wp_^T)  (split-bf16 3-pass MFMA)
//  att_s: logits (exp form, paired rcps) + softmax; writes normalized a (bf16)
//  ac_k : c[t,b,:] = a[t,b,:] @ v[:,b,:]  (64 per-b GEMMs on MFMA)
//  gi_k : Gi = c@W_ih^T + b_ih  (bf16)
//  rec_k v12: NEW — 8 groups x 4 BLOCKS x 8 WAVES (512-thread blocks).
//    Halves sync participants (barrier target 8 -> 4): fewer serialized MALL
//    flag-adds + less arrival skew per step. Sync primitive byte-identical to
//    the r14-proven path (sc1 publish -> drain -> syncthreads -> tid0 agent
//    add -> poll). Each block owns 128 j's; per-wave code unchanged.

typedef float f32x4 __attribute__((ext_vector_type(4)));
typedef short s16x8 __attribute__((ext_vector_type(8)));
typedef short s16x4 __attribute__((ext_vector_type(4)));
typedef unsigned int u32x2 __attribute__((ext_vector_type(2)));

static __device__ __forceinline__ float rcp_fast(float x) { return __builtin_amdgcn_rcpf(x); }
static __device__ __forceinline__ float tanh_fast(float x) {
    float e = __expf(2.0f * x);
    return 1.0f - 2.0f * rcp_fast(e + 1.0f);
}
static __device__ __forceinline__ float sigmoid_fast(float x) {
    return rcp_fast(1.0f + __expf(-x));
}
static __device__ __forceinline__ unsigned short f2bf(float x) {
    __hip_bfloat16 h = __float2bfloat16(x);
    return *(unsigned short*)&h;
}
static __device__ __forceinline__ float bf2f(unsigned short b) {
    union { unsigned u; float f; } v; v.u = ((unsigned)b) << 16;
    return v.f;
}
static __device__ __forceinline__ s16x8 pack8(f32x4 a, f32x4 b) {
    s16x8 r;
    r[0] = (short)f2bf(a[0]); r[1] = (short)f2bf(a[1]);
    r[2] = (short)f2bf(a[2]); r[3] = (short)f2bf(a[3]);
    r[4] = (short)f2bf(b[0]); r[5] = (short)f2bf(b[1]);
    r[6] = (short)f2bf(b[2]); r[7] = (short)f2bf(b[3]);
    return r;
}
static __device__ __forceinline__ void split8(f32x4 a, f32x4 b, s16x8* hi, s16x8* lo) {
    s16x8 h, l;
#pragma unroll
    for (int e = 0; e < 4; e++) {
        unsigned short hh = f2bf(a[e]); h[e] = (short)hh;
        l[e] = (short)f2bf(a[e] - bf2f(hh));
    }
#pragma unroll
    for (int e = 0; e < 4; e++) {
        unsigned short hh = f2bf(b[e]); h[4 + e] = (short)hh;
        l[4 + e] = (short)f2bf(b[e] - bf2f(hh));
    }
    *hi = h; *lo = l;
}
static __device__ __forceinline__ f32x4 mfma16(s16x8 a, s16x8 b, f32x4 c) {
    return __builtin_amdgcn_mfma_f32_16x16x32_bf16(a, b, c, 0, 0, 0);
}
static __device__ __forceinline__ unsigned ld_agent(const unsigned* p) {
    return __hip_atomic_load(p, __ATOMIC_RELAXED, __HIP_MEMORY_SCOPE_AGENT);
}
static __device__ __forceinline__ void add_agent(unsigned* p, unsigned v) {
    __hip_atomic_fetch_add(p, v, __ATOMIC_RELAXED, __HIP_MEMORY_SCOPE_AGENT);
}
static __device__ __forceinline__ void vm_drain() {
    asm volatile("s_waitcnt vmcnt(0)" ::: "memory");
}

// ---------------------------------------------------------------------------
// Fused P/Q GEMM (r17)
// ---------------------------------------------------------------------------
__global__ __launch_bounds__(256, 2)
void pq_k(const float* __restrict__ v, const float* __restrict__ Wp,
          const float* __restrict__ Wp_, float* __restrict__ Ep,
          float* __restrict__ Eq)
{
    const int bm = blockIdx.x, bn = blockIdx.y;
    const int tid = threadIdx.x;
    const int w = tid >> 6, lane = tid & 63;
    const int l15 = lane & 15, l4 = lane >> 4;

    __shared__ unsigned short Al[128 * 72 * 2];
    __shared__ unsigned short Wl[128 * 72 * 2];
    const int LOFS = 128 * 72;

    f32x4 accP[4][4], accQ[4][4];
#pragma unroll
    for (int i = 0; i < 4; i++)
#pragma unroll
        for (int j = 0; j < 4; j++) {
            accP[i][j] = (f32x4){0.f, 0.f, 0.f, 0.f};
            accQ[i][j] = (f32x4){0.f, 0.f, 0.f, 0.f};
        }

    const int srow = tid >> 1, shalf = tid & 1;
    const float* Asrc  = v   + (size_t)(bm * 128 + srow) * 512 + shalf * 32;
    const float* W1src = Wp  + (size_t)(bn * 128 + srow) * 512 + shalf * 32;
    const float* W2src = Wp_ + (size_t)(bn * 128 + srow) * 512 + shalf * 32;
    unsigned short* Adst = Al + srow * 72 + shalf * 32;
    unsigned short* Wdst = Wl + srow * 72 + shalf * 32;

    for (int k0 = 0; k0 < 512; k0 += 64) {
        f32x4 w2x[4], w2y[4];
#pragma unroll
        for (int j = 0; j < 4; j++) {
            w2x[j] = *(const f32x4*)(W2src + k0 + j * 8);
            w2y[j] = *(const f32x4*)(W2src + k0 + j * 8 + 4);
        }
        __syncthreads();
#pragma unroll
        for (int j = 0; j < 4; j++) {
            f32x4 x = *(const f32x4*)(Asrc + k0 + j * 8);
            f32x4 y = *(const f32x4*)(Asrc + k0 + j * 8 + 4);
            s16x8 hi, lo; split8(x, y, &hi, &lo);
            *(s16x8*)(Adst + j * 8) = hi;
            *(s16x8*)(Adst + LOFS + j * 8) = lo;
        }
#pragma unroll
        for (int j = 0; j < 4; j++) {
            f32x4 x = *(const f32x4*)(W1src + k0 + j * 8);
            f32x4 y = *(const f32x4*)(W1src + k0 + j * 8 + 4);
            s16x8 hi, lo; split8(x, y, &hi, &lo);
            *(s16x8*)(Wdst + j * 8) = hi;
            *(s16x8*)(Wdst + LOFS + j * 8) = lo;
        }
        __syncthreads();

#pragma unroll
        for (int kt = 0; kt < 2; kt++) {
            s16x8 afh[4], afl[4], bfh[4], bfl[4];
#pragma unroll
            for (int mb = 0; mb < 4; mb++) {
                afh[mb] = *(const s16x8*)(Al + ((w & 1) * 64 + mb * 16 + l15) * 72 + kt * 32 + l4 * 8);
                afl[mb] = *(const s16x8*)(Al + LOFS + ((w & 1) * 64 + mb * 16 + l15) * 72 + kt * 32 + l4 * 8);
            }
#pragma unroll
            for (int nb = 0; nb < 4; nb++) {
                bfh[nb] = *(const s16x8*)(Wl + ((w >> 1) * 64 + nb * 16 + l15) * 72 + kt * 32 + l4 * 8);
                bfl[nb] = *(const s16x8*)(Wl + LOFS + ((w >> 1) * 64 + nb * 16 + l15) * 72 + kt * 32 + l4 * 8);
            }
#pragma unroll
            for (int mb = 0; mb < 4; mb++)
#pragma unroll
                for (int nb = 0; nb < 4; nb++) {
                    accP[mb][nb] = mfma16(afh[mb], bfh[nb], accP[mb][nb]);
                    accP[mb][nb] = mfma16(afh[mb], bfl[nb], accP[mb][nb]);
                    accP[mb][nb] = mfma16(afl[mb], bfh[nb], accP[mb][nb]);
                }
        }

        __syncthreads();
#pragma unroll
        for (int j = 0; j < 4; j++) {
            s16x8 hi, lo; split8(w2x[j], w2y[j], &hi, &lo);
            *(s16x8*)(Wdst + j * 8) = hi;
            *(s16x8*)(Wdst + LOFS + j * 8) = lo;
        }
        __syncthreads();

#pragma unroll
        for (int kt = 0; kt < 2; kt++) {
            s16x8 afh[4], afl[4], bfh[4], bfl[4];
#pragma unroll
            for (int mb = 0; mb < 4; mb++) {
                afh[mb] = *(const s16x8*)(Al + ((w & 1) * 64 + mb * 16 + l15) * 72 + kt * 32 + l4 * 8);
                afl[mb] = *(const s16x8*)(Al + LOFS + ((w & 1) * 64 + mb * 16 + l15) * 72 + kt * 32 + l4 * 8);
            }
#pragma unroll
            for (int nb = 0; nb < 4; nb++) {
                bfh[nb] = *(const s16x8*)(Wl + ((w >> 1) * 64 + nb * 16 + l15) * 72 + kt * 32 + l4 * 8);
                bfl[nb] = *(const s16x8*)(Wl + LOFS + ((w >> 1) * 64 + nb * 16 + l15) * 72 + kt * 32 + l4 * 8);
            }
#pragma unroll
            for (int mb = 0; mb < 4; mb++)
#pragma unroll
                for (int nb = 0; nb < 4; nb++) {
                    accQ[mb][nb] = mfma16(afh[mb], bfh[nb], accQ[mb][nb]);
                    accQ[mb][nb] = mfma16(afh[mb], bfl[nb], accQ[mb][nb]);
                    accQ[mb][nb] = mfma16(afl[mb], bfh[nb], accQ[mb][nb]);
                }
        }
    }

    const int m0 = bm * 128 + (w & 1) * 64;
    const int n0 = bn * 128 + (w >> 1) * 64;
#pragma unroll
    for (int nb = 0; nb < 4; nb++) {
        const int n = n0 + nb * 16 + l15;
#pragma unroll
        for (int mb = 0; mb < 4; mb++) {
#pragma unroll
            for (int i = 0; i < 4; i++) {
                const int m = m0 + mb * 16 + l4 * 4 + i;
                Ep[(size_t)m * 512 + n] = __expf(2.0f * accP[mb][nb][i]);
                Eq[(size_t)m * 512 + n] = __expf(2.0f * accQ[mb][nb][i]);
            }
        }
    }
}

// ---------------------------------------------------------------------------
// att_s (r16-proven)
// ---------------------------------------------------------------------------
__global__ __launch_bounds__(512, 4)
void att_s(const float* __restrict__ Ept, const float* __restrict__ Eqt,
           const float* __restrict__ Vv, unsigned short* __restrict__ abuf)
{
    const int tblk = blockIdx.x, b = blockIdx.y;
    const int tid = threadIdx.x;
    const int w = tid >> 6, lane = tid & 63;
    const int t_in = lane >> 5, sl = lane & 31;
    const int t_loc = w * 2 + t_in;
    const int tg = tblk * 16 + t_loc;

    __shared__ float sbuf[16][513];
    __shared__ float qst[8][640];
    __shared__ float zinv[16];

    float Ep[16], Vb2[16];
    float VbS = 0.0f;
    {
        const float* pp = Ept + ((size_t)tg * 64 + b) * 512 + sl * 16;
        const float* vb = Vv + (size_t)b * 512 + sl * 16;
#pragma unroll
        for (int j = 0; j < 4; j++) {
            f32x4 x = *(const f32x4*)(pp + j * 4);
            f32x4 y = *(const f32x4*)(vb + j * 4);
#pragma unroll
            for (int e = 0; e < 4; e++) {
                Ep[j * 4 + e] = x[e];
                Vb2[j * 4 + e] = 2.0f * y[e];
                VbS += y[e];
            }
        }
    }

    for (int l0 = 0; l0 < 512; l0 += 8) {
        __syncthreads();
        {
            const int row = tid >> 6;
            const int cb = (tid & 63) * 8;
            const float* src = Eqt + ((size_t)(l0 + row) * 64 + b) * 512 + cb;
            const int f0 = cb + 4 * (cb >> 4);
            *(f32x4*)(&qst[row][f0])     = *(const f32x4*)(src);
            *(f32x4*)(&qst[row][f0 + 4]) = *(const f32x4*)(src + 4);
        }
        __syncthreads();
        for (int l = 0; l < 8; l++) {
            const float* qrow = &qst[l][sl * 20];
            float a0 = VbS, a1 = 0.f;
#pragma unroll
            for (int j = 0; j < 4; j++) {
                f32x4 q = *(const f32x4*)(qrow + j * 4);
                float d0 = fmaf(Ep[4 * j + 0], q[0], 1.0f);
                float d1 = fmaf(Ep[4 * j + 1], q[1], 1.0f);
                float d2 = fmaf(Ep[4 * j + 2], q[2], 1.0f);
                float d3 = fmaf(Ep[4 * j + 3], q[3], 1.0f);
                float m01 = d0 * d1;
                float m23 = d2 * d3;
                float n01 = Vb2[4 * j + 0] * d1;
                n01 = fmaf(Vb2[4 * j + 1], d0, n01);
                float n23 = Vb2[4 * j + 2] * d3;
                n23 = fmaf(Vb2[4 * j + 3], d2, n23);
                a0 = fmaf(-n01, rcp_fast(m01), a0);
                a1 = fmaf(-n23, rcp_fast(m23), a1);
            }
            float accp = a0 + a1;
#pragma unroll
            for (int m = 1; m < 32; m <<= 1) accp += __shfl_xor(accp, m, 64);
            if (sl == 0) sbuf[t_loc][l0 + l] = accp;
        }
    }
    __syncthreads();

    {
        const int tr = tid >> 5;
        const int i = tid & 31;
        float m = -1e30f;
        for (int l = i; l < 512; l += 32) m = fmaxf(m, sbuf[tr][l]);
#pragma unroll
        for (int mm = 1; mm < 32; mm <<= 1) m = fmaxf(m, __shfl_xor(m, mm, 64));
        float z = 0.0f;
        for (int l = i; l < 512; l += 32) {
            float e = __expf(sbuf[tr][l] - m);
            sbuf[tr][l] = e;
            z += e;
        }
#pragma unroll
        for (int mm = 1; mm < 32; mm <<= 1) z += __shfl_xor(z, mm, 64);
        if (i == 0) zinv[tr] = rcp_fast(z);
    }
    __syncthreads();

    {
        const int tr = tid >> 5;
        const int i = tid & 31;
        const float zi = zinv[tr];
        const int tg2 = tblk * 16 + tr;
        unsigned short* dst = abuf + ((size_t)b * 512 + tg2) * 512 + i * 16;
        s16x8 o0, o1;
#pragma unroll
        for (int e = 0; e < 8; e++) o0[e] = (short)f2bf(sbuf[tr][i * 16 + e] * zi);
#pragma unroll
        for (int e = 0; e < 8; e++) o1[e] = (short)f2bf(sbuf[tr][i * 16 + 8 + e] * zi);
        *(s16x8*)(dst)     = o0;
        *(s16x8*)(dst + 8) = o1;
    }
}

// ---------------------------------------------------------------------------
// ac_k (r16-proven)
// ---------------------------------------------------------------------------
__global__ __launch_bounds__(256, 2)
void ac_k(const unsigned short* __restrict__ abuf,
          const float* __restrict__ vin,
          unsigned short* __restrict__ cbuf)
{
    const int bt = blockIdx.x, bd = blockIdx.y, b = blockIdx.z;
    const int tid = threadIdx.x;
    const int w = tid >> 6, lane = tid & 63;
    const int l15 = lane & 15, l4 = lane >> 4;

    __shared__ unsigned short Al[128 * 72];
    __shared__ unsigned short Wt[128 * 72];

    f32x4 acc[4][4];
#pragma unroll
    for (int i = 0; i < 4; i++)
#pragma unroll
        for (int j = 0; j < 4; j++) acc[i][j] = (f32x4){0.f, 0.f, 0.f, 0.f};

    const int srow = tid >> 1, shalf = tid & 1;
    const unsigned short* Asrc = abuf + ((size_t)b * 512 + bt * 128 + srow) * 512 + shalf * 32;
    unsigned short* Adst = Al + srow * 72 + shalf * 32;

    const int lpair = tid & 31;
    const int dgrp  = tid >> 5;

    for (int k0 = 0; k0 < 512; k0 += 64) {
        __syncthreads();
#pragma unroll
        for (int j = 0; j < 4; j++)
            *(s16x8*)(Adst + j * 8) = *(const s16x8*)(Asrc + k0 + j * 8);
        {
            const float* r0 = vin + ((size_t)(k0 + 2 * lpair) * 64 + b) * 512 + bd * 128 + dgrp * 16;
            const float* r1 = r0 + 64 * 512;
            f32x4 x0[4], x1[4];
#pragma unroll
            for (int j = 0; j < 4; j++) {
                x0[j] = *(const f32x4*)(r0 + j * 4);
                x1[j] = *(const f32x4*)(r1 + j * 4);
            }
            unsigned* wt32 = (unsigned*)Wt;
#pragma unroll
            for (int j = 0; j < 4; j++)
#pragma unroll
                for (int e = 0; e < 4; e++) {
                    const int d = dgrp * 16 + j * 4 + e;
                    wt32[d * 36 + lpair] =
                        (unsigned)f2bf(x0[j][e]) | ((unsigned)f2bf(x1[j][e]) << 16);
                }
        }
        __syncthreads();

#pragma unroll
        for (int kt = 0; kt < 2; kt++) {
            s16x8 afh[4], bfh[4];
#pragma unroll
            for (int mb = 0; mb < 4; mb++)
                afh[mb] = *(const s16x8*)(Al + ((w & 1) * 64 + mb * 16 + l15) * 72 + kt * 32 + l4 * 8);
#pragma unroll
            for (int nb = 0; nb < 4; nb++)
                bfh[nb] = *(const s16x8*)(Wt + ((w >> 1) * 64 + nb * 16 + l15) * 72 + kt * 32 + l4 * 8);
#pragma unroll
            for (int mb = 0; mb < 4; mb++)
#pragma unroll
                for (int nb = 0; nb < 4; nb++)
                    acc[mb][nb] = mfma16(afh[mb], bfh[nb], acc[mb][nb]);
        }
    }

    const int t0 = bt * 128 + (w & 1) * 64;
    const int d0 = bd * 128 + (w >> 1) * 64;
#pragma unroll
    for (int nb = 0; nb < 4; nb++) {
        const int d = d0 + nb * 16 + l15;
#pragma unroll
        for (int mb = 0; mb < 4; mb++) {
#pragma unroll
            for (int i = 0; i < 4; i++) {
                const int t = t0 + mb * 16 + l4 * 4 + i;
                cbuf[((size_t)t * 64 + b) * 512 + d] = f2bf(acc[mb][nb][i]);
            }
        }
    }
}

// ---------------------------------------------------------------------------
// gi_k (r14-proven)
// ---------------------------------------------------------------------------
__global__ __launch_bounds__(256, 2)
void gi_k(const unsigned short* __restrict__ Ap, const float* __restrict__ Wp,
          const float* __restrict__ bias, unsigned short* __restrict__ outp, int N)
{
    const int bm = blockIdx.x, bn = blockIdx.y;
    const int tid = threadIdx.x;
    const int w = tid >> 6, lane = tid & 63;
    const int l15 = lane & 15, l4 = lane >> 4;

    __shared__ unsigned short Al[128 * 72];
    __shared__ unsigned short Wl[128 * 72];

    f32x4 acc[4][4];
#pragma unroll
    for (int i = 0; i < 4; i++)
#pragma unroll
        for (int j = 0; j < 4; j++) acc[i][j] = (f32x4){0.f, 0.f, 0.f, 0.f};

    const int srow = tid >> 1, shalf = tid & 1;
    const unsigned short* Asrcb = Ap + (size_t)(bm * 128 + srow) * 512 + shalf * 32;
    const float* Wsrc = Wp + (size_t)(bn * 128 + srow) * 512 + shalf * 32;
    unsigned short* Adst = Al + srow * 72 + shalf * 32;
    unsigned short* Wdst = Wl + srow * 72 + shalf * 32;

    for (int k0 = 0; k0 < 512; k0 += 64) {
        __syncthreads();
#pragma unroll
        for (int j = 0; j < 4; j++)
            *(s16x8*)(Adst + j * 8) = *(const s16x8*)(Asrcb + k0 + j * 8);
#pragma unroll
        for (int j = 0; j < 4; j++) {
            f32x4 x = *(const f32x4*)(Wsrc + k0 + j * 8);
            f32x4 y = *(const f32x4*)(Wsrc + k0 + j * 8 + 4);
            *(s16x8*)(Wdst + j * 8) = pack8(x, y);
        }
        __syncthreads();

#pragma unroll
        for (int kt = 0; kt < 2; kt++) {
            s16x8 afh[4], bfh[4];
#pragma unroll
            for (int mb = 0; mb < 4; mb++)
                afh[mb] = *(const s16x8*)(Al + ((w & 1) * 64 + mb * 16 + l15) * 72 + kt * 32 + l4 * 8);
#pragma unroll
            for (int nb = 0; nb < 4; nb++)
                bfh[nb] = *(const s16x8*)(Wl + ((w >> 1) * 64 + nb * 16 + l15) * 72 + kt * 32 + l4 * 8);
#pragma unroll
            for (int mb = 0; mb < 4; mb++)
#pragma unroll
                for (int nb = 0; nb < 4; nb++)
                    acc[mb][nb] = mfma16(afh[mb], bfh[nb], acc[mb][nb]);
        }
    }

    const int m0 = bm * 128 + (w & 1) * 64;
    const int n0 = bn * 128 + (w >> 1) * 64;
#pragma unroll
    for (int nb = 0; nb < 4; nb++) {
        const int n = n0 + nb * 16 + l15;
        const float bv = bias[n];
#pragma unroll
        for (int mb = 0; mb < 4; mb++) {
#pragma unroll
            for (int i = 0; i < 4; i++) {
                const int m = m0 + mb * 16 + l4 * 4 + i;
                outp[(size_t)m * N + n] = f2bf(acc[mb][nb][i] + bv);
            }
        }
    }
}

// ---------------------------------------------------------------------------
// rec_k v12 — 32 blocks x 512 threads (8 waves): g = bid>>2 (8 b's),
// sub = bid&3 owns j in [sub*128, +128); wave w (0..7) owns 16 j's.
// Barrier target 4 (was 8). Sync primitive identical to r14.
// ---------------------------------------------------------------------------
__global__ __launch_bounds__(512, 1)
void rec_k(const unsigned short* __restrict__ Gi,
           const float* __restrict__ Whh, const float* __restrict__ bhh,
           const float* __restrict__ h0,
           unsigned int* __restrict__ hb32,
           unsigned int* __restrict__ bar,
           float* __restrict__ hs)
{
    const int tid = threadIdx.x;
    const int g = blockIdx.x >> 2;
    const int sub = blockIdx.x & 3;
    const int w = tid >> 6;                 // 0..7
    const int lane = tid & 63;
    const int l15 = lane & 15, l4 = lane >> 4;
    const int b  = g * 8 + (l15 & 7);
    const int jb = sub * 128 + w * 16;
    const int jrow = l4 * 4;
    const bool writer = (l15 < 8);

    s16x8 wf[3][16];
#pragma unroll
    for (int gg = 0; gg < 3; gg++) {
        const float* wr = Whh + (size_t)(gg * 512 + jb + l15) * 512 + l4 * 8;
#pragma unroll
        for (int c = 0; c < 16; c++) {
            f32x4 x = *(const f32x4*)(wr + c * 32);
            f32x4 y = *(const f32x4*)(wr + c * 32 + 4);
            wf[gg][c] = pack8(x, y);
        }
    }

    float bh_r[4], bh_z[4], bh_n[4];
#pragma unroll
    for (int i = 0; i < 4; i++) {
        bh_r[i] = bhh[jb + jrow + i];
        bh_z[i] = bhh[512 + jb + jrow + i];
        bh_n[i] = bhh[1024 + jb + jrow + i];
    }
    float hp[4];
#pragma unroll
    for (int i = 0; i < 4; i++) hp[i] = h0[(size_t)b * 512 + jb + jrow + i];

    unsigned* barA = bar + g * 512;

    s16x4 g0, g1, g2;
    {
        const unsigned short* gp = Gi + (size_t)b * 1536 + jb + jrow;
        g0 = *(const s16x4*)(gp);
        g1 = *(const s16x4*)(gp + 512);
        g2 = *(const s16x4*)(gp + 1024);
    }

#define LDH(i, lit) asm volatile("global_load_dwordx4 %0, %1, off offset:" lit " sc1" \
                                 : "=v"(hfrag2[i]) : "v"(src) : "memory");

    for (int t = 0; t < 512; t++) {
        s16x8 hfrag[16];
        if (t == 0) {
            const float* hr = h0 + (size_t)b * 512 + l4 * 8;
#pragma unroll
            for (int c = 0; c < 16; c++) {
                f32x4 x = *(const f32x4*)(hr + c * 32);
                f32x4 y = *(const f32x4*)(hr + c * 32 + 4);
                hfrag[c] = pack8(x, y);
            }
        } else {
            const unsigned int* src = hb32 + (t & 1) * 16384 + b * 256 + l4 * 4;
            s16x8 hfrag2[16];
            LDH(0, "0")   LDH(1, "64")  LDH(2, "128")  LDH(3, "192")
            LDH(4, "256") LDH(5, "320") LDH(6, "384")  LDH(7, "448")
            LDH(8, "512") LDH(9, "576") LDH(10, "640") LDH(11, "704")
            LDH(12, "768") LDH(13, "832") LDH(14, "896") LDH(15, "960")
            vm_drain();
            __builtin_amdgcn_sched_barrier(0);
#pragma unroll
            for (int c = 0; c < 16; c++) hfrag[c] = hfrag2[c];
        }

        f32x4 acc0 = {0.f, 0.f, 0.f, 0.f};
        f32x4 acc1 = {0.f, 0.f, 0.f, 0.f};
        f32x4 acc2 = {0.f, 0.f, 0.f, 0.f};
#pragma unroll
        for (int c = 0; c < 16; c++) {
            acc0 = mfma16(wf[0][c], hfrag[c], acc0);
            acc1 = mfma16(wf[1][c], hfrag[c], acc1);
            acc2 = mfma16(wf[2][c], hfrag[c], acc2);
        }

#pragma unroll
        for (int i = 0; i < 4; i++) {
            float rr = sigmoid_fast(bf2f((unsigned short)g0[i]) + acc0[i] + bh_r[i]);
            float zz = sigmoid_fast(bf2f((unsigned short)g1[i]) + acc1[i] + bh_z[i]);
            float nn = tanh_fast(bf2f((unsigned short)g2[i]) + rr * (acc2[i] + bh_n[i]));
            hp[i] = fmaf(zz, hp[i] - nn, nn);
        }

        float* hso = hs + ((size_t)t * 64 + b) * 512 + jb + jrow;
        f32x4 hv = {hp[0], hp[1], hp[2], hp[3]};

        if (t < 511) {
            if (writer) {
                u32x2 pp;
                pp[0] = (unsigned)f2bf(hp[0]) | ((unsigned)f2bf(hp[1]) << 16);
                pp[1] = (unsigned)f2bf(hp[2]) | ((unsigned)f2bf(hp[3]) << 16);
                unsigned int* dst = hb32 + ((t + 1) & 1) * 16384 + b * 256 + ((jb + jrow) >> 1);
                asm volatile("global_store_dwordx2 %0, %1, off sc1"
                             :: "v"(dst), "v"(pp) : "memory");
            }
            vm_drain();
            __syncthreads();
            if (tid == 0) add_agent(barA + t, 1u);

            if (writer) *(f32x4*)hso = hv;
            s16x4 n0, n1, n2;
            {
                const unsigned short* gp = Gi + ((size_t)(t + 1) * 64 + b) * 1536 + jb + jrow;
                n0 = *(const s16x4*)(gp);
                n1 = *(const s16x4*)(gp + 512);
                n2 = *(const s16x4*)(gp + 1024);
            }

            for (;;) {
                unsigned vb = ld_agent(barA + t);
                if (vb >= 4u) break;
                __builtin_amdgcn_s_sleep(1);
            }
            g0 = n0; g1 = n1; g2 = n2;
        } else {
            if (writer) *(f32x4*)hso = hv;
        }
    }
#undef LDH
}

// ---------------------------------------------------------------------------
// ws layout (bytes):
//   Ep   : [0, 64Mi)      f32
//   Eq   : [64Mi, 128Mi)  f32
//   abuf : [128Mi, 160Mi) bf16
//   c    : [160Mi, 192Mi) bf16
//   Gi   : [0, 96Mi)      bf16 (overlays Ep/Eq/abuf — dead after ac_k)
//   hb32 : [192Mi, +128Ki) | bar : next 16Ki (memset per launch)
// ---------------------------------------------------------------------------
extern "C" void kernel_launch(void* const* d_in, const int* in_sizes, int n_in,
                              void* d_out, int out_size, void* d_ws, size_t ws_size,
                              hipStream_t stream)
{
    (void)in_sizes; (void)n_in; (void)out_size; (void)ws_size;
    const float* v   = (const float*)d_in[0];
    const float* h0  = (const float*)d_in[1];
    const float* Vv  = (const float*)d_in[2];
    const float* Wp  = (const float*)d_in[3];
    const float* Wp_ = (const float*)d_in[4];
    const float* Wih = (const float*)d_in[5];
    const float* Whh = (const float*)d_in[6];
    const float* bih = (const float*)d_in[7];
    const float* bhh = (const float*)d_in[8];
    float* hs = (float*)d_out;

    char* ws = (char*)d_ws;
    float* Ep = (float*)(ws);
    float* Eq = (float*)(ws + 67108864ULL);
    unsigned short* abuf = (unsigned short*)(ws + 134217728ULL);
    unsigned short* cb   = (unsigned short*)(ws + 167772160ULL);
    unsigned short* Gi   = (unsigned short*)(ws);
    unsigned int*   hb32 = (unsigned int*)(ws + 201326592ULL);
    unsigned int*   bar  = (unsigned int*)(ws + 201326592ULL + 131072ULL);

    hipMemsetAsync(bar, 0, 4096 * sizeof(unsigned int), stream);

    pq_k<<<dim3(256, 4), 256, 0, stream>>>(v, Wp, Wp_, Ep, Eq);

    att_s<<<dim3(32, 64), 512, 0, stream>>>(Ep, Eq, Vv, abuf);

    ac_k<<<dim3(4, 4, 64), 256, 0, stream>>>(abuf, v, cb);

    gi_k<<<dim3(256, 12), 256, 0, stream>>>(cb, Wih, bih, Gi, 1536);

    rec_k<<<dim3(32), 512, 0, stream>>>(Gi, Whh, bhh, h0, hb32, bar, hs);
}

// Round 19
// 3508.513 us; speedup vs baseline: 1.8214x; 1.8214x over previous
//
#include <hip/hip_runtime.h>
#include <hip/hip_bf16.h>

// L=512, B=64, D=H=512, 3H=1536.  (r19 = revert to r17-proven best config;
// r18's 512-thread rec_k spilled W_hh from registers: VGPR capped at 128 <
// 192 needed -> scratch traffic, 2.5x regression.)
//  pq_k : Ep = exp(2·v@Wp^T), Eq = exp(2·v@Wp_^T)  (split-bf16 3-pass MFMA)
//  att_s: logits (exp form, paired rcps) + softmax; writes normalized a (bf16)
//  ac_k : c[t,b,:] = a[t,b,:] @ v[:,b,:]  (64 per-b GEMMs on MFMA)
//  gi_k : Gi = c@W_ih^T + b_ih  (bf16)
//  rec_k: r14-proven: 64 blocks x 256 thr, 8 groups x 8 blocks x 4 waves,
//         W_hh register-resident, sc1 h exchange (dwordx4), agent flag + poll.

typedef float f32x4 __attribute__((ext_vector_type(4)));
typedef short s16x8 __attribute__((ext_vector_type(8)));
typedef short s16x4 __attribute__((ext_vector_type(4)));
typedef unsigned int u32x2 __attribute__((ext_vector_type(2)));

static __device__ __forceinline__ float rcp_fast(float x) { return __builtin_amdgcn_rcpf(x); }
static __device__ __forceinline__ float tanh_fast(float x) {
    float e = __expf(2.0f * x);
    return 1.0f - 2.0f * rcp_fast(e + 1.0f);
}
static __device__ __forceinline__ float sigmoid_fast(float x) {
    return rcp_fast(1.0f + __expf(-x));
}
static __device__ __forceinline__ unsigned short f2bf(float x) {
    __hip_bfloat16 h = __float2bfloat16(x);
    return *(unsigned short*)&h;
}
static __device__ __forceinline__ float bf2f(unsigned short b) {
    union { unsigned u; float f; } v; v.u = ((unsigned)b) << 16;
    return v.f;
}
static __device__ __forceinline__ s16x8 pack8(f32x4 a, f32x4 b) {
    s16x8 r;
    r[0] = (short)f2bf(a[0]); r[1] = (short)f2bf(a[1]);
    r[2] = (short)f2bf(a[2]); r[3] = (short)f2bf(a[3]);
    r[4] = (short)f2bf(b[0]); r[5] = (short)f2bf(b[1]);
    r[6] = (short)f2bf(b[2]); r[7] = (short)f2bf(b[3]);
    return r;
}
static __device__ __forceinline__ void split8(f32x4 a, f32x4 b, s16x8* hi, s16x8* lo) {
    s16x8 h, l;
#pragma unroll
    for (int e = 0; e < 4; e++) {
        unsigned short hh = f2bf(a[e]); h[e] = (short)hh;
        l[e] = (short)f2bf(a[e] - bf2f(hh));
    }
#pragma unroll
    for (int e = 0; e < 4; e++) {
        unsigned short hh = f2bf(b[e]); h[4 + e] = (short)hh;
        l[4 + e] = (short)f2bf(b[e] - bf2f(hh));
    }
    *hi = h; *lo = l;
}
static __device__ __forceinline__ f32x4 mfma16(s16x8 a, s16x8 b, f32x4 c) {
    return __builtin_amdgcn_mfma_f32_16x16x32_bf16(a, b, c, 0, 0, 0);
}
static __device__ __forceinline__ unsigned ld_agent(const unsigned* p) {
    return __hip_atomic_load(p, __ATOMIC_RELAXED, __HIP_MEMORY_SCOPE_AGENT);
}
static __device__ __forceinline__ void add_agent(unsigned* p, unsigned v) {
    __hip_atomic_fetch_add(p, v, __ATOMIC_RELAXED, __HIP_MEMORY_SCOPE_AGENT);
}
static __device__ __forceinline__ void vm_drain() {
    asm volatile("s_waitcnt vmcnt(0)" ::: "memory");
}

// ---------------------------------------------------------------------------
// Fused P/Q GEMM (r17-proven)
// ---------------------------------------------------------------------------
__global__ __launch_bounds__(256, 2)
void pq_k(const float* __restrict__ v, const float* __restrict__ Wp,
          const float* __restrict__ Wp_, float* __restrict__ Ep,
          float* __restrict__ Eq)
{
    const int bm = blockIdx.x, bn = blockIdx.y;
    const int tid = threadIdx.x;
    const int w = tid >> 6, lane = tid & 63;
    const int l15 = lane & 15, l4 = lane >> 4;

    __shared__ unsigned short Al[128 * 72 * 2];
    __shared__ unsigned short Wl[128 * 72 * 2];
    const int LOFS = 128 * 72;

    f32x4 accP[4][4], accQ[4][4];
#pragma unroll
    for (int i = 0; i < 4; i++)
#pragma unroll
        for (int j = 0; j < 4; j++) {
            accP[i][j] = (f32x4){0.f, 0.f, 0.f, 0.f};
            accQ[i][j] = (f32x4){0.f, 0.f, 0.f, 0.f};
        }

    const int srow = tid >> 1, shalf = tid & 1;
    const float* Asrc  = v   + (size_t)(bm * 128 + srow) * 512 + shalf * 32;
    const float* W1src = Wp  + (size_t)(bn * 128 + srow) * 512 + shalf * 32;
    const float* W2src = Wp_ + (size_t)(bn * 128 + srow) * 512 + shalf * 32;
    unsigned short* Adst = Al + srow * 72 + shalf * 32;
    unsigned short* Wdst = Wl + srow * 72 + shalf * 32;

    for (int k0 = 0; k0 < 512; k0 += 64) {
        f32x4 w2x[4], w2y[4];
#pragma unroll
        for (int j = 0; j < 4; j++) {
            w2x[j] = *(const f32x4*)(W2src + k0 + j * 8);
            w2y[j] = *(const f32x4*)(W2src + k0 + j * 8 + 4);
        }
        __syncthreads();
#pragma unroll
        for (int j = 0; j < 4; j++) {
            f32x4 x = *(const f32x4*)(Asrc + k0 + j * 8);
            f32x4 y = *(const f32x4*)(Asrc + k0 + j * 8 + 4);
            s16x8 hi, lo; split8(x, y, &hi, &lo);
            *(s16x8*)(Adst + j * 8) = hi;
            *(s16x8*)(Adst + LOFS + j * 8) = lo;
        }
#pragma unroll
        for (int j = 0; j < 4; j++) {
            f32x4 x = *(const f32x4*)(W1src + k0 + j * 8);
            f32x4 y = *(const f32x4*)(W1src + k0 + j * 8 + 4);
            s16x8 hi, lo; split8(x, y, &hi, &lo);
            *(s16x8*)(Wdst + j * 8) = hi;
            *(s16x8*)(Wdst + LOFS + j * 8) = lo;
        }
        __syncthreads();

#pragma unroll
        for (int kt = 0; kt < 2; kt++) {
            s16x8 afh[4], afl[4], bfh[4], bfl[4];
#pragma unroll
            for (int mb = 0; mb < 4; mb++) {
                afh[mb] = *(const s16x8*)(Al + ((w & 1) * 64 + mb * 16 + l15) * 72 + kt * 32 + l4 * 8);
                afl[mb] = *(const s16x8*)(Al + LOFS + ((w & 1) * 64 + mb * 16 + l15) * 72 + kt * 32 + l4 * 8);
            }
#pragma unroll
            for (int nb = 0; nb < 4; nb++) {
                bfh[nb] = *(const s16x8*)(Wl + ((w >> 1) * 64 + nb * 16 + l15) * 72 + kt * 32 + l4 * 8);
                bfl[nb] = *(const s16x8*)(Wl + LOFS + ((w >> 1) * 64 + nb * 16 + l15) * 72 + kt * 32 + l4 * 8);
            }
#pragma unroll
            for (int mb = 0; mb < 4; mb++)
#pragma unroll
                for (int nb = 0; nb < 4; nb++) {
                    accP[mb][nb] = mfma16(afh[mb], bfh[nb], accP[mb][nb]);
                    accP[mb][nb] = mfma16(afh[mb], bfl[nb], accP[mb][nb]);
                    accP[mb][nb] = mfma16(afl[mb], bfh[nb], accP[mb][nb]);
                }
        }

        __syncthreads();
#pragma unroll
        for (int j = 0; j < 4; j++) {
            s16x8 hi, lo; split8(w2x[j], w2y[j], &hi, &lo);
            *(s16x8*)(Wdst + j * 8) = hi;
            *(s16x8*)(Wdst + LOFS + j * 8) = lo;
        }
        __syncthreads();

#pragma unroll
        for (int kt = 0; kt < 2; kt++) {
            s16x8 afh[4], afl[4], bfh[4], bfl[4];
#pragma unroll
            for (int mb = 0; mb < 4; mb++) {
                afh[mb] = *(const s16x8*)(Al + ((w & 1) * 64 + mb * 16 + l15) * 72 + kt * 32 + l4 * 8);
                afl[mb] = *(const s16x8*)(Al + LOFS + ((w & 1) * 64 + mb * 16 + l15) * 72 + kt * 32 + l4 * 8);
            }
#pragma unroll
            for (int nb = 0; nb < 4; nb++) {
                bfh[nb] = *(const s16x8*)(Wl + ((w >> 1) * 64 + nb * 16 + l15) * 72 + kt * 32 + l4 * 8);
                bfl[nb] = *(const s16x8*)(Wl + LOFS + ((w >> 1) * 64 + nb * 16 + l15) * 72 + kt * 32 + l4 * 8);
            }
#pragma unroll
            for (int mb = 0; mb < 4; mb++)
#pragma unroll
                for (int nb = 0; nb < 4; nb++) {
                    accQ[mb][nb] = mfma16(afh[mb], bfh[nb], accQ[mb][nb]);
                    accQ[mb][nb] = mfma16(afh[mb], bfl[nb], accQ[mb][nb]);
                    accQ[mb][nb] = mfma16(afl[mb], bfh[nb], accQ[mb][nb]);
                }
        }
    }

    const int m0 = bm * 128 + (w & 1) * 64;
    const int n0 = bn * 128 + (w >> 1) * 64;
#pragma unroll
    for (int nb = 0; nb < 4; nb++) {
        const int n = n0 + nb * 16 + l15;
#pragma unroll
        for (int mb = 0; mb < 4; mb++) {
#pragma unroll
            for (int i = 0; i < 4; i++) {
                const int m = m0 + mb * 16 + l4 * 4 + i;
                Ep[(size_t)m * 512 + n] = __expf(2.0f * accP[mb][nb][i]);
                Eq[(size_t)m * 512 + n] = __expf(2.0f * accQ[mb][nb][i]);
            }
        }
    }
}

// ---------------------------------------------------------------------------
// att_s (r16-proven)
// ---------------------------------------------------------------------------
__global__ __launch_bounds__(512, 4)
void att_s(const float* __restrict__ Ept, const float* __restrict__ Eqt,
           const float* __restrict__ Vv, unsigned short* __restrict__ abuf)
{
    const int tblk = blockIdx.x, b = blockIdx.y;
    const int tid = threadIdx.x;
    const int w = tid >> 6, lane = tid & 63;
    const int t_in = lane >> 5, sl = lane & 31;
    const int t_loc = w * 2 + t_in;
    const int tg = tblk * 16 + t_loc;

    __shared__ float sbuf[16][513];
    __shared__ float qst[8][640];
    __shared__ float zinv[16];

    float Ep[16], Vb2[16];
    float VbS = 0.0f;
    {
        const float* pp = Ept + ((size_t)tg * 64 + b) * 512 + sl * 16;
        const float* vb = Vv + (size_t)b * 512 + sl * 16;
#pragma unroll
        for (int j = 0; j < 4; j++) {
            f32x4 x = *(const f32x4*)(pp + j * 4);
            f32x4 y = *(const f32x4*)(vb + j * 4);
#pragma unroll
            for (int e = 0; e < 4; e++) {
                Ep[j * 4 + e] = x[e];
                Vb2[j * 4 + e] = 2.0f * y[e];
                VbS += y[e];
            }
        }
    }

    for (int l0 = 0; l0 < 512; l0 += 8) {
        __syncthreads();
        {
            const int row = tid >> 6;
            const int cb = (tid & 63) * 8;
            const float* src = Eqt + ((size_t)(l0 + row) * 64 + b) * 512 + cb;
            const int f0 = cb + 4 * (cb >> 4);
            *(f32x4*)(&qst[row][f0])     = *(const f32x4*)(src);
            *(f32x4*)(&qst[row][f0 + 4]) = *(const f32x4*)(src + 4);
        }
        __syncthreads();
        for (int l = 0; l < 8; l++) {
            const float* qrow = &qst[l][sl * 20];
            float a0 = VbS, a1 = 0.f;
#pragma unroll
            for (int j = 0; j < 4; j++) {
                f32x4 q = *(const f32x4*)(qrow + j * 4);
                float d0 = fmaf(Ep[4 * j + 0], q[0], 1.0f);
                float d1 = fmaf(Ep[4 * j + 1], q[1], 1.0f);
                float d2 = fmaf(Ep[4 * j + 2], q[2], 1.0f);
                float d3 = fmaf(Ep[4 * j + 3], q[3], 1.0f);
                float m01 = d0 * d1;
                float m23 = d2 * d3;
                float n01 = Vb2[4 * j + 0] * d1;
                n01 = fmaf(Vb2[4 * j + 1], d0, n01);
                float n23 = Vb2[4 * j + 2] * d3;
                n23 = fmaf(Vb2[4 * j + 3], d2, n23);
                a0 = fmaf(-n01, rcp_fast(m01), a0);
                a1 = fmaf(-n23, rcp_fast(m23), a1);
            }
            float accp = a0 + a1;
#pragma unroll
            for (int m = 1; m < 32; m <<= 1) accp += __shfl_xor(accp, m, 64);
            if (sl == 0) sbuf[t_loc][l0 + l] = accp;
        }
    }
    __syncthreads();

    {
        const int tr = tid >> 5;
        const int i = tid & 31;
        float m = -1e30f;
        for (int l = i; l < 512; l += 32) m = fmaxf(m, sbuf[tr][l]);
#pragma unroll
        for (int mm = 1; mm < 32; mm <<= 1) m = fmaxf(m, __shfl_xor(m, mm, 64));
        float z = 0.0f;
        for (int l = i; l < 512; l += 32) {
            float e = __expf(sbuf[tr][l] - m);
            sbuf[tr][l] = e;
            z += e;
        }
#pragma unroll
        for (int mm = 1; mm < 32; mm <<= 1) z += __shfl_xor(z, mm, 64);
        if (i == 0) zinv[tr] = rcp_fast(z);
    }
    __syncthreads();

    {
        const int tr = tid >> 5;
        const int i = tid & 31;
        const float zi = zinv[tr];
        const int tg2 = tblk * 16 + tr;
        unsigned short* dst = abuf + ((size_t)b * 512 + tg2) * 512 + i * 16;
        s16x8 o0, o1;
#pragma unroll
        for (int e = 0; e < 8; e++) o0[e] = (short)f2bf(sbuf[tr][i * 16 + e] * zi);
#pragma unroll
        for (int e = 0; e < 8; e++) o1[e] = (short)f2bf(sbuf[tr][i * 16 + 8 + e] * zi);
        *(s16x8*)(dst)     = o0;
        *(s16x8*)(dst + 8) = o1;
    }
}

// ---------------------------------------------------------------------------
// ac_k (r16-proven)
// ---------------------------------------------------------------------------
__global__ __launch_bounds__(256, 2)
void ac_k(const unsigned short* __restrict__ abuf,
          const float* __restrict__ vin,
          unsigned short* __restrict__ cbuf)
{
    const int bt = blockIdx.x, bd = blockIdx.y, b = blockIdx.z;
    const int tid = threadIdx.x;
    const int w = tid >> 6, lane = tid & 63;
    const int l15 = lane & 15, l4 = lane >> 4;

    __shared__ unsigned short Al[128 * 72];
    __shared__ unsigned short Wt[128 * 72];

    f32x4 acc[4][4];
#pragma unroll
    for (int i = 0; i < 4; i++)
#pragma unroll
        for (int j = 0; j < 4; j++) acc[i][j] = (f32x4){0.f, 0.f, 0.f, 0.f};

    const int srow = tid >> 1, shalf = tid & 1;
    const unsigned short* Asrc = abuf + ((size_t)b * 512 + bt * 128 + srow) * 512 + shalf * 32;
    unsigned short* Adst = Al + srow * 72 + shalf * 32;

    const int lpair = tid & 31;
    const int dgrp  = tid >> 5;

    for (int k0 = 0; k0 < 512; k0 += 64) {
        __syncthreads();
#pragma unroll
        for (int j = 0; j < 4; j++)
            *(s16x8*)(Adst + j * 8) = *(const s16x8*)(Asrc + k0 + j * 8);
        {
            const float* r0 = vin + ((size_t)(k0 + 2 * lpair) * 64 + b) * 512 + bd * 128 + dgrp * 16;
            const float* r1 = r0 + 64 * 512;
            f32x4 x0[4], x1[4];
#pragma unroll
            for (int j = 0; j < 4; j++) {
                x0[j] = *(const f32x4*)(r0 + j * 4);
                x1[j] = *(const f32x4*)(r1 + j * 4);
            }
            unsigned* wt32 = (unsigned*)Wt;
#pragma unroll
            for (int j = 0; j < 4; j++)
#pragma unroll
                for (int e = 0; e < 4; e++) {
                    const int d = dgrp * 16 + j * 4 + e;
                    wt32[d * 36 + lpair] =
                        (unsigned)f2bf(x0[j][e]) | ((unsigned)f2bf(x1[j][e]) << 16);
                }
        }
        __syncthreads();

#pragma unroll
        for (int kt = 0; kt < 2; kt++) {
            s16x8 afh[4], bfh[4];
#pragma unroll
            for (int mb = 0; mb < 4; mb++)
                afh[mb] = *(const s16x8*)(Al + ((w & 1) * 64 + mb * 16 + l15) * 72 + kt * 32 + l4 * 8);
#pragma unroll
            for (int nb = 0; nb < 4; nb++)
                bfh[nb] = *(const s16x8*)(Wt + ((w >> 1) * 64 + nb * 16 + l15) * 72 + kt * 32 + l4 * 8);
#pragma unroll
            for (int mb = 0; mb < 4; mb++)
#pragma unroll
                for (int nb = 0; nb < 4; nb++)
                    acc[mb][nb] = mfma16(afh[mb], bfh[nb], acc[mb][nb]);
        }
    }

    const int t0 = bt * 128 + (w & 1) * 64;
    const int d0 = bd * 128 + (w >> 1) * 64;
#pragma unroll
    for (int nb = 0; nb < 4; nb++) {
        const int d = d0 + nb * 16 + l15;
#pragma unroll
        for (int mb = 0; mb < 4; mb++) {
#pragma unroll
            for (int i = 0; i < 4; i++) {
                const int t = t0 + mb * 16 + l4 * 4 + i;
                cbuf[((size_t)t * 64 + b) * 512 + d] = f2bf(acc[mb][nb][i]);
            }
        }
    }
}

// ---------------------------------------------------------------------------
// gi_k (r14-proven)
// ---------------------------------------------------------------------------
__global__ __launch_bounds__(256, 2)
void gi_k(const unsigned short* __restrict__ Ap, const float* __restrict__ Wp,
          const float* __restrict__ bias, unsigned short* __restrict__ outp, int N)
{
    const int bm = blockIdx.x, bn = blockIdx.y;
    const int tid = threadIdx.x;
    const int w = tid >> 6, lane = tid & 63;
    const int l15 = lane & 15, l4 = lane >> 4;

    __shared__ unsigned short Al[128 * 72];
    __shared__ unsigned short Wl[128 * 72];

    f32x4 acc[4][4];
#pragma unroll
    for (int i = 0; i < 4; i++)
#pragma unroll
        for (int j = 0; j < 4; j++) acc[i][j] = (f32x4){0.f, 0.f, 0.f, 0.f};

    const int srow = tid >> 1, shalf = tid & 1;
    const unsigned short* Asrcb = Ap + (size_t)(bm * 128 + srow) * 512 + shalf * 32;
    const float* Wsrc = Wp + (size_t)(bn * 128 + srow) * 512 + shalf * 32;
    unsigned short* Adst = Al + srow * 72 + shalf * 32;
    unsigned short* Wdst = Wl + srow * 72 + shalf * 32;

    for (int k0 = 0; k0 < 512; k0 += 64) {
        __syncthreads();
#pragma unroll
        for (int j = 0; j < 4; j++)
            *(s16x8*)(Adst + j * 8) = *(const s16x8*)(Asrcb + k0 + j * 8);
#pragma unroll
        for (int j = 0; j < 4; j++) {
            f32x4 x = *(const f32x4*)(Wsrc + k0 + j * 8);
            f32x4 y = *(const f32x4*)(Wsrc + k0 + j * 8 + 4);
            *(s16x8*)(Wdst + j * 8) = pack8(x, y);
        }
        __syncthreads();

#pragma unroll
        for (int kt = 0; kt < 2; kt++) {
            s16x8 afh[4], bfh[4];
#pragma unroll
            for (int mb = 0; mb < 4; mb++)
                afh[mb] = *(const s16x8*)(Al + ((w & 1) * 64 + mb * 16 + l15) * 72 + kt * 32 + l4 * 8);
#pragma unroll
            for (int nb = 0; nb < 4; nb++)
                bfh[nb] = *(const s16x8*)(Wl + ((w >> 1) * 64 + nb * 16 + l15) * 72 + kt * 32 + l4 * 8);
#pragma unroll
            for (int mb = 0; mb < 4; mb++)
#pragma unroll
                for (int nb = 0; nb < 4; nb++)
                    acc[mb][nb] = mfma16(afh[mb], bfh[nb], acc[mb][nb]);
        }
    }

    const int m0 = bm * 128 + (w & 1) * 64;
    const int n0 = bn * 128 + (w >> 1) * 64;
#pragma unroll
    for (int nb = 0; nb < 4; nb++) {
        const int n = n0 + nb * 16 + l15;
        const float bv = bias[n];
#pragma unroll
        for (int mb = 0; mb < 4; mb++) {
#pragma unroll
            for (int i = 0; i < 4; i++) {
                const int m = m0 + mb * 16 + l4 * 4 + i;
                outp[(size_t)m * N + n] = f2bf(acc[mb][nb][i] + bv);
            }
        }
    }
}

// ---------------------------------------------------------------------------
// rec_k v11 (r14/r17-proven, 256-thread, W_hh register-resident)
// ---------------------------------------------------------------------------
__global__ __launch_bounds__(256, 1)
void rec_k(const unsigned short* __restrict__ Gi,
           const float* __restrict__ Whh, const float* __restrict__ bhh,
           const float* __restrict__ h0,
           unsigned int* __restrict__ hb32,
           unsigned int* __restrict__ bar,
           float* __restrict__ hs)
{
    const int tid = threadIdx.x;
    const int g = blockIdx.x >> 3;
    const int sub = blockIdx.x & 7;
    const int w = tid >> 6;
    const int lane = tid & 63;
    const int l15 = lane & 15, l4 = lane >> 4;
    const int b  = g * 8 + (l15 & 7);
    const int jb = sub * 64 + w * 16;
    const int jrow = l4 * 4;
    const bool writer = (l15 < 8);

    s16x8 wf[3][16];
#pragma unroll
    for (int gg = 0; gg < 3; gg++) {
        const float* wr = Whh + (size_t)(gg * 512 + jb + l15) * 512 + l4 * 8;
#pragma unroll
        for (int c = 0; c < 16; c++) {
            f32x4 x = *(const f32x4*)(wr + c * 32);
            f32x4 y = *(const f32x4*)(wr + c * 32 + 4);
            wf[gg][c] = pack8(x, y);
        }
    }

    float bh_r[4], bh_z[4], bh_n[4];
#pragma unroll
    for (int i = 0; i < 4; i++) {
        bh_r[i] = bhh[jb + jrow + i];
        bh_z[i] = bhh[512 + jb + jrow + i];
        bh_n[i] = bhh[1024 + jb + jrow + i];
    }
    float hp[4];
#pragma unroll
    for (int i = 0; i < 4; i++) hp[i] = h0[(size_t)b * 512 + jb + jrow + i];

    unsigned* barA = bar + g * 512;

    s16x4 g0, g1, g2;
    {
        const unsigned short* gp = Gi + (size_t)b * 1536 + jb + jrow;
        g0 = *(const s16x4*)(gp);
        g1 = *(const s16x4*)(gp + 512);
        g2 = *(const s16x4*)(gp + 1024);
    }

#define LDH(i, lit) asm volatile("global_load_dwordx4 %0, %1, off offset:" lit " sc1" \
                                 : "=v"(hfrag2[i]) : "v"(src) : "memory");

    for (int t = 0; t < 512; t++) {
        s16x8 hfrag[16];
        if (t == 0) {
            const float* hr = h0 + (size_t)b * 512 + l4 * 8;
#pragma unroll
            for (int c = 0; c < 16; c++) {
                f32x4 x = *(const f32x4*)(hr + c * 32);
                f32x4 y = *(const f32x4*)(hr + c * 32 + 4);
                hfrag[c] = pack8(x, y);
            }
        } else {
            const unsigned int* src = hb32 + (t & 1) * 16384 + b * 256 + l4 * 4;
            s16x8 hfrag2[16];
            LDH(0, "0")   LDH(1, "64")  LDH(2, "128")  LDH(3, "192")
            LDH(4, "256") LDH(5, "320") LDH(6, "384")  LDH(7, "448")
            LDH(8, "512") LDH(9, "576") LDH(10, "640") LDH(11, "704")
            LDH(12, "768") LDH(13, "832") LDH(14, "896") LDH(15, "960")
            vm_drain();
            __builtin_amdgcn_sched_barrier(0);
#pragma unroll
            for (int c = 0; c < 16; c++) hfrag[c] = hfrag2[c];
        }

        f32x4 acc0 = {0.f, 0.f, 0.f, 0.f};
        f32x4 acc1 = {0.f, 0.f, 0.f, 0.f};
        f32x4 acc2 = {0.f, 0.f, 0.f, 0.f};
#pragma unroll
        for (int c = 0; c < 16; c++) {
            acc0 = mfma16(wf[0][c], hfrag[c], acc0);
            acc1 = mfma16(wf[1][c], hfrag[c], acc1);
            acc2 = mfma16(wf[2][c], hfrag[c], acc2);
        }

#pragma unroll
        for (int i = 0; i < 4; i++) {
            float rr = sigmoid_fast(bf2f((unsigned short)g0[i]) + acc0[i] + bh_r[i]);
            float zz = sigmoid_fast(bf2f((unsigned short)g1[i]) + acc1[i] + bh_z[i]);
            float nn = tanh_fast(bf2f((unsigned short)g2[i]) + rr * (acc2[i] + bh_n[i]));
            hp[i] = fmaf(zz, hp[i] - nn, nn);
        }

        float* hso = hs + ((size_t)t * 64 + b) * 512 + jb + jrow;
        f32x4 hv = {hp[0], hp[1], hp[2], hp[3]};

        if (t < 511) {
            if (writer) {
                u32x2 pp;
                pp[0] = (unsigned)f2bf(hp[0]) | ((unsigned)f2bf(hp[1]) << 16);
                pp[1] = (unsigned)f2bf(hp[2]) | ((unsigned)f2bf(hp[3]) << 16);
                unsigned int* dst = hb32 + ((t + 1) & 1) * 16384 + b * 256 + ((jb + jrow) >> 1);
                asm volatile("global_store_dwordx2 %0, %1, off sc1"
                             :: "v"(dst), "v"(pp) : "memory");
            }
            vm_drain();
            __syncthreads();
            if (tid == 0) add_agent(barA + t, 1u);

            if (writer) *(f32x4*)hso = hv;
            s16x4 n0, n1, n2;
            {
                const unsigned short* gp = Gi + ((size_t)(t + 1) * 64 + b) * 1536 + jb + jrow;
                n0 = *(const s16x4*)(gp);
                n1 = *(const s16x4*)(gp + 512);
                n2 = *(const s16x4*)(gp + 1024);
            }

            for (;;) {
                unsigned vb = ld_agent(barA + t);
                if (vb >= 8u) break;
                __builtin_amdgcn_s_sleep(1);
            }
            g0 = n0; g1 = n1; g2 = n2;
        } else {
            if (writer) *(f32x4*)hso = hv;
        }
    }
#undef LDH
}

// ---------------------------------------------------------------------------
// ws layout (bytes):
//   Ep   : [0, 64Mi)      f32
//   Eq   : [64Mi, 128Mi)  f32
//   abuf : [128Mi, 160Mi) bf16
//   c    : [160Mi, 192Mi) bf16
//   Gi   : [0, 96Mi)      bf16 (overlays Ep/Eq/abuf — dead after ac_k)
//   hb32 : [192Mi, +128Ki) | bar : next 16Ki (memset per launch)
// ---------------------------------------------------------------------------
extern "C" void kernel_launch(void* const* d_in, const int* in_sizes, int n_in,
                              void* d_out, int out_size, void* d_ws, size_t ws_size,
                              hipStream_t stream)
{
    (void)in_sizes; (void)n_in; (void)out_size; (void)ws_size;
    const float* v   = (const float*)d_in[0];
    const float* h0  = (const float*)d_in[1];
    const float* Vv  = (const float*)d_in[2];
    const float* Wp  = (const float*)d_in[3];
    const float* Wp_ = (const float*)d_in[4];
    const float* Wih = (const float*)d_in[5];
    const float* Whh = (const float*)d_in[6];
    const float* bih = (const float*)d_in[7];
    const float* bhh = (const float*)d_in[8];
    float* hs = (float*)d_out;

    char* ws = (char*)d_ws;
    float* Ep = (float*)(ws);
    float* Eq = (float*)(ws + 67108864ULL);
    unsigned short* abuf = (unsigned short*)(ws + 134217728ULL);
    unsigned short* cb   = (unsigned short*)(ws + 167772160ULL);
    unsigned short* Gi   = (unsigned short*)(ws);
    unsigned int*   hb32 = (unsigned int*)(ws + 201326592ULL);
    unsigned int*   bar  = (unsigned int*)(ws + 201326592ULL + 131072ULL);

    hipMemsetAsync(bar, 0, 4096 * sizeof(unsigned int), stream);

    pq_k<<<dim3(256, 4), 256, 0, stream>>>(v, Wp, Wp_, Ep, Eq);

    att_s<<<dim3(32, 64), 512, 0, stream>>>(Ep, Eq, Vv, abuf);

    ac_k<<<dim3(4, 4, 64), 256, 0, stream>>>(abuf, v, cb);

    gi_k<<<dim3(256, 12), 256, 0, stream>>>(cb, Wih, bih, Gi, 1536);

    rec_k<<<dim3(64), 256, 0, stream>>>(Gi, Whh, bhh, h0, hb32, bar, hs);
}